// Round 4
// baseline (254.294 us; speedup 1.0000x reference)
//
#include <hip/hip_runtime.h>
#include <hip/hip_bf16.h>
#include <stdint.h>
#include <math.h>

// ===== Problem constants =====
#define BB 8
#define LL 4096
#define HH 4
#define DD 8      // IN_DIM
#define VV 4      // FFN_V
#define DEPTH 8   // FFN_DEPTH
#define NBIT 8
#define NROW 131072   // B*L*H
#define CHUNK 64
#define NCHUNK 64     // L / CHUNK

#define PARTITIONABLE 1
#define MATH_XLA_CPU 1

__device__ __forceinline__ uint32_t rotl32(uint32_t v, int r){ return (v<<r)|(v>>(32-r)); }

__device__ __forceinline__ void tf2x32(uint32_t k0, uint32_t k1, uint32_t x0, uint32_t x1,
                                       uint32_t& o0, uint32_t& o1){
  uint32_t ks2 = k0 ^ k1 ^ 0x1BD11BDAu;
  x0 += k0; x1 += k1;
  x0+=x1; x1=rotl32(x1,13); x1^=x0;
  x0+=x1; x1=rotl32(x1,15); x1^=x0;
  x0+=x1; x1=rotl32(x1,26); x1^=x0;
  x0+=x1; x1=rotl32(x1, 6); x1^=x0;
  x0+=k1; x1+=ks2+1u;
  x0+=x1; x1=rotl32(x1,17); x1^=x0;
  x0+=x1; x1=rotl32(x1,29); x1^=x0;
  x0+=x1; x1=rotl32(x1,16); x1^=x0;
  x0+=x1; x1=rotl32(x1,24); x1^=x0;
  x0+=ks2; x1+=k0+2u;
  x0+=x1; x1=rotl32(x1,13); x1^=x0;
  x0+=x1; x1=rotl32(x1,15); x1^=x0;
  x0+=x1; x1=rotl32(x1,26); x1^=x0;
  x0+=x1; x1=rotl32(x1, 6); x1^=x0;
  x0+=k0; x1+=k1+3u;
  x0+=x1; x1=rotl32(x1,17); x1^=x0;
  x0+=x1; x1=rotl32(x1,29); x1^=x0;
  x0+=x1; x1=rotl32(x1,16); x1^=x0;
  x0+=x1; x1=rotl32(x1,24); x1^=x0;
  x0+=k1; x1+=ks2+4u;
  x0+=x1; x1=rotl32(x1,13); x1^=x0;
  x0+=x1; x1=rotl32(x1,15); x1^=x0;
  x0+=x1; x1=rotl32(x1,26); x1^=x0;
  x0+=x1; x1=rotl32(x1, 6); x1^=x0;
  x0+=ks2; x1+=k0+5u;
  o0 = x0; o1 = x1;
}

struct K2 { uint32_t a, b; };
__device__ __forceinline__ K2 kfold(K2 k, uint32_t d){
  K2 r; tf2x32(k.a, k.b, 0u, d, r.a, r.b); return r;
}

__device__ __forceinline__ uint32_t rbits(K2 k, uint32_t p){
#if PARTITIONABLE
  uint32_t o0, o1; tf2x32(k.a, k.b, 0u, p, o0, o1); return o0 ^ o1;
#endif
}

__device__ __forceinline__ float bits2u(uint32_t b){
  return __uint_as_float((b >> 9) | 0x3f800000u) - 1.0f;
}

// ===== Bit-exact XLA-CPU style math (Cephes/Eigen structure, strict f32, no FMA) =====
__device__ __forceinline__ float xla_expf(float x){
  #pragma clang fp contract(off)
  const float exp_hi = 88.3762626647950f;
  const float exp_lo = -88.3762626647949f;
  const float log2e  = 1.44269504088896341f;
  const float c1 = 0.693359375f;
  const float c2 = -2.12194440e-4f;
  float xc = fmaxf(fminf(x, exp_hi), exp_lo);
  float fx = floorf(xc * log2e + 0.5f);
  float tmp = fx * c1;
  float z1  = fx * c2;
  float r = xc - tmp;
  r = r - z1;
  float z = r * r;
  float y = 1.9875691500E-4f;
  y = y * r + 1.3981999507E-3f;
  y = y * r + 8.3334519073E-3f;
  y = y * r + 4.1665795894E-2f;
  y = y * r + 1.6666665459E-1f;
  y = y * r + 5.0000001201E-1f;
  y = y * z + r;
  y = y + 1.0f;
  int emm0 = (int)fx + 127;
  float scale = __int_as_float(emm0 << 23);
  return fmaxf(y * scale, x);
}

__device__ __forceinline__ float xla_logf(float a){
  #pragma clang fp contract(off)
  float x = fmaxf(a, __uint_as_float(0x00800000u));
  uint32_t bits = __float_as_uint(x);
  int em = (int)(bits >> 23) - 126;
  x = __uint_as_float((bits & 0x007fffffu) | 0x3f000000u);
  float e = (float)em;
  bool mlt = x < 0.707106781186547524f;
  float tmp1 = mlt ? x : 0.0f;
  float xm = x - 1.0f;
  e = e - (mlt ? 1.0f : 0.0f);
  xm = xm + tmp1;
  float z = xm * xm;
  float y = 7.0376836292E-2f;
  y = y * xm + (-1.1514610310E-1f);
  y = y * xm + 1.1676998740E-1f;
  y = y * xm + (-1.2420140846E-1f);
  y = y * xm + 1.4249322787E-1f;
  y = y * xm + (-1.6668057665E-1f);
  y = y * xm + 2.0000714765E-1f;
  y = y * xm + (-2.4999993993E-1f);
  y = y * xm + 3.3333331174E-1f;
  y = y * xm;
  y = y * z;
  y = e * (-2.12194440e-4f) + y;
  y = y - 0.5f * z;
  float res = xm + y;
  res = e * 0.693359375f + res;
  return res;
}

__device__ __forceinline__ float xla_log1pf(float x){
  #pragma clang fp contract(off)
  if (fabsf(x) < 1e-4f){
    return ((-0.5f * x) + 1.0f) * x;
  }
  return xla_logf(1.0f + x);
}

__device__ __forceinline__ float xla_logaddexp(float a, float b){
  #pragma clang fp contract(off)
  float m = fmaxf(a, b);
  float d = a - b;
  return m + xla_log1pf(xla_expf(-fabsf(d)));
}

template<int NV>
__device__ __forceinline__ float neg_lse_neg(const float* v){
  #pragma clang fp contract(off)
  float m = -v[0];
  #pragma unroll
  for (int i = 1; i < NV; i++) m = fmaxf(m, -v[i]);
  float s = 0.f;
  #pragma unroll
  for (int i = 0; i < NV; i++) s = s + xla_expf((-v[i]) - m);
  return -(xla_logf(s) + m);
}

// sigmoid exactly as XLA LogisticExpander: 1/(1+exp(-w)) — used for both
// precompute (k_pre) and in-loop (routing bern). MUST stay one definition.
__device__ __forceinline__ float xla_sigmoid(float w){
  #pragma clang fp contract(off)
  float e = xla_expf(-w);
  return 1.0f / (1.0f + e);
}

// fast soft-AND for analog-only paths: -logaddexp(-a,-b). andf(x, 1e30f)==x.
__device__ __forceinline__ float andf(float a, float b){
  float na = -a, nb = -b;
  float m = fmaxf(na, nb);
  float d = fabsf(na - nb);
  return -(m + log1pf(expf(-d)));
}
#define AND_IDENT 1e30f

// ===== k_pre: sigmoid tables + flag + s0 + uniform threefry keys =====
// grid: 592 blocks x 256 (covers 131072 sigT + 16320 sigFK + 4096 sigFV)
__global__ __launch_bounds__(256) void k_pre(const uint32_t* xw, int* flag,
                      const float* s0w, int* s0code, float* s0s,
                      const float* fk, const float* fv, const float* table,
                      float* sigT, float* sigFK, float* sigFV, uint32_t* keys){
  int i = blockIdx.x * 256 + threadIdx.x;
  if (i < 131072)              sigT [i]          = xla_sigmoid(table[i]);
  else if (i < 131072+16320)   sigFK[i-131072]   = xla_sigmoid(fk[i-131072]);
  else if (i < 131072+16320+4096) sigFV[i-131072-16320] = xla_sigmoid(fv[i-131072-16320]);

  if (blockIdx.x == 0){
    __shared__ int any;
    int t = threadIdx.x;
    if (t == 0) any = 0;
    __syncthreads();
    int bad = 0;
    for (int k = t; k < 1024; k += 256){
      uint32_t w = xw[k];
      if (w != 0u && w != 1u && w != 0x3F800000u) bad = 1;
    }
    if (bad) atomicOr(&any, 1);
    __syncthreads();
    if (t == 0) *flag = any;

    if (t < 32){
      int b = t >> 2, h = t & 3;
      K2 root{0u, 42u};
      K2 sk = kfold(root, 3u);
      float v[NBIT];
      uint32_t code = 0;
      #pragma unroll
      for (int j = 0; j < NBIT; j++){
        float w = s0w[h*NBIT + j];
        uint32_t p = (uint32_t)((b*4 + h)*NBIT + j);
        float u = bits2u(rbits(sk, p));
        bool bit = u < xla_sigmoid(w);
        code |= (bit ? 1u : 0u) << (NBIT - 1 - j);
        v[j] = bit ? w : -w;
      }
      s0code[t] = (int)code;
      s0s[t]    = neg_lse_neg<NBIT>(v);
    }
    if (t == 0){
      K2 root{0u, 42u};
      K2 rngT = kfold(root, 1u);
      for (int d = 0; d < DEPTH; d++){
        K2 kd = kfold(rngT, (uint32_t)d);
        keys[2*d] = kd.a; keys[2*d+1] = kd.b;
        K2 lk = kfold(rngT, 100u + (uint32_t)d);
        keys[16+2*d] = lk.a; keys[16+2*d+1] = lk.b;
      }
      K2 vk = kfold(rngT, 999u);
      keys[32] = vk.a; keys[33] = vk.b;
    }
  }
}

// ===== k_ffn: tree-FFN -> xcode + xss (bit-critical) =====
__global__ __launch_bounds__(256) void k_ffn(const void* xraw, const float* xs,
                                             const float* sigFK,
                                             const float* fv, const float* sigFV,
                                             const uint32_t* keys,
                                             uint8_t* xcode, float* xss, const int* flag){
  int r = blockIdx.x * blockDim.x + threadIdx.x;
  if (r >= NROW) return;
  int n = r >> 2;
  int h = r & 3;
  bool u8mode = (*flag != 0);
  const uint8_t* x8   = (const uint8_t*)xraw;
  const uint32_t* x32 = (const uint32_t*)xraw;

  // L[j][(b2<<1)|b1] = logaddexp(-logaddexp(-b1, qs), -logaddexp(-b2, -qs))
  // computed with the identical op sequence the reference uses per (d,j).
  float L0[DD], L1[DD], L2[DD], L3[DD];
  #pragma unroll
  for (int j = 0; j < DD; j++){
    bool qb = u8mode ? (x8[n*DD + j] != 0) : (x32[n*DD + j] != 0u);
    float v = xs[n*DD + j];
    float q = qb ? v : -v;
    float A0 = -xla_logaddexp(-0.0f, q);
    float A1 = -xla_logaddexp(-1.0f, q);
    float B0 = -xla_logaddexp(-0.0f, -q);
    float B1 = -xla_logaddexp(-1.0f, -q);
    L0[j] = xla_logaddexp(A0, B0);
    L1[j] = xla_logaddexp(A1, B0);
    L2[j] = xla_logaddexp(A0, B1);
    L3[j] = xla_logaddexp(A1, B1);
  }

  uint32_t ix = 0;
  float support = 0.f;
  for (int d = 0; d < DEPTH; d++){
    K2 kd{keys[2*d], keys[2*d+1]};
    const float* skw = sigFK + (size_t)(h*255 + (1<<d) - 1 + (int)ix) * 16;
    float lor[DD];
    #pragma unroll
    for (int j = 0; j < DD; j++){
      uint32_t p1 = (uint32_t)r * 16u + 2u*(uint32_t)j;
      float u1 = bits2u(rbits(kd, p1));
      float u2 = bits2u(rbits(kd, p1 + 1u));
      bool b1 = u1 < skw[2*j];
      bool b2 = u2 < skw[2*j + 1];
      float t01 = b1 ? L1[j] : L0[j];
      float t23 = b1 ? L3[j] : L2[j];
      lor[j] = b2 ? t23 : t01;
    }
    float lor_s = neg_lse_neg<DD>(lor);
    K2 lk{keys[16+2*d], keys[16+2*d+1]};
    float ul = bits2u(rbits(lk, (uint32_t)r));
    bool lb = ul < xla_sigmoid(lor_s);
    float ls = lb ? lor_s : -lor_s;
    ix = 2u*ix + (lb ? 1u : 0u);
    support = (d == 0) ? ls : -xla_logaddexp(-support, -ls);
  }

  K2 vk{keys[32], keys[33]};
  const float* vw  = fv    + (size_t)(h*256 + (int)ix) * VV;
  const float* svw = sigFV + (size_t)(h*256 + (int)ix) * VV;
  float vs[VV];
  uint32_t code = 0;
  #pragma unroll
  for (int c = 0; c < VV; c++){
    float u = bits2u(rbits(vk, (uint32_t)r*4u + (uint32_t)c));
    bool b = u < svw[c];
    code |= (b ? 1u : 0u) << (VV - 1 - c);
    float sv = b ? vw[c] : -vw[c];
    vs[c] = -xla_logaddexp(-sv, -support);
  }
  xcode[r] = (uint8_t)code;
  xss[r]   = neg_lse_neg<VV>(vs);
}

// ===== k_table: tcode + tabs (bit-critical, sigmoid precomputed) =====
__global__ __launch_bounds__(256) void k_table(const float* table, const float* sigT,
                                               uint8_t* tcode, float* tabs){
  int idx = blockIdx.x * blockDim.x + threadIdx.x;
  if (idx >= 131072) return;
  int rem = idx & 16383;
  K2 root{0u, 42u};
  K2 tk = kfold(root, 2u);
  float4 w0 = *(const float4*)(table + (size_t)rem*NBIT);
  float4 w1 = *(const float4*)(table + (size_t)rem*NBIT + 4);
  float4 g0 = *(const float4*)(sigT  + (size_t)rem*NBIT);
  float4 g1 = *(const float4*)(sigT  + (size_t)rem*NBIT + 4);
  float w[NBIT] = {w0.x,w0.y,w0.z,w0.w,w1.x,w1.y,w1.z,w1.w};
  float g[NBIT] = {g0.x,g0.y,g0.z,g0.w,g1.x,g1.y,g1.z,g1.w};
  float v[NBIT];
  uint32_t code = 0;
  #pragma unroll
  for (int j = 0; j < NBIT; j++){
    float u = bits2u(rbits(tk, (uint32_t)idx * 8u + (uint32_t)j));
    bool bit = u < g[j];
    code |= (bit ? 1u : 0u) << (NBIT - 1 - j);
    v[j] = bit ? w[j] : -w[j];
  }
  tcode[idx] = (uint8_t)code;
  tabs[idx]  = neg_lse_neg<NBIT>(v);
}

// ===== Phase A: per-chunk all-state map F (states only) =====
__global__ __launch_bounds__(256) void k_A(const uint8_t* tcode, const uint8_t* xcode,
                                           uint8_t* F){
  int blk = blockIdx.x;          // (b*4+h)*64 + c
  int c  = blk & 63;
  int bh = blk >> 6;
  int b = bh >> 2, h = bh & 3;
  __shared__ int4 sT4[256];
  __shared__ uint8_t sXC[CHUNK];
  uint8_t* sT = (uint8_t*)sT4;
  int t = threadIdx.x;
  const int rowbase = (b*64 + h*16) * 256;
  sT4[t] = ((const int4*)(tcode + rowbase))[t];
  if (t < CHUNK){
    int l = c*CHUNK + t;
    sXC[t] = xcode[(b*LL + l)*HH + h];
  }
  __syncthreads();
  int cur = t;
  #pragma unroll 8
  for (int k = 0; k < CHUNK; k++){
    cur = sT[(int)sXC[k]*256 + cur];
  }
  F[(size_t)blk*256 + t] = (uint8_t)cur;
}

// ===== Phase B: sequential carryZ across chunks, 32 chains =====
__global__ __launch_bounds__(256) void k_B(const uint8_t* F, const int* s0code, int* carryZ){
  int bh = blockIdx.x;
  __shared__ int4 sF4[1024];
  uint8_t* sF = (uint8_t*)sF4;
  int t = threadIdx.x;
  const int4* src = (const int4*)(F + (size_t)bh*16384);
  for (int i = t; i < 1024; i += 256) sF4[i] = src[i];
  __syncthreads();
  if (t == 0){
    int z = s0code[bh];
    for (int c = 0; c < NCHUNK; c++){ carryZ[bh*NCHUNK + c] = z; z = sF[c*256 + z]; }
  }
}

// ===== Phase C1: chase from carry-in + parallel scores + wave prefix-scan =====
__global__ __launch_bounds__(64) void k_C1(const uint8_t* tcode, const float* tabs,
                                           const uint8_t* xcode, const float* xss,
                                           const int* carryZ,
                                           uint8_t* zOut, float* P, float* T){
  int blk = blockIdx.x;          // (b*4+h)*64 + c
  int c  = blk & 63;
  int bh = blk >> 6;
  int b = bh >> 2, h = bh & 3;
  __shared__ int4 sT4[256];
  uint8_t* sT = (uint8_t*)sT4;
  int t = threadIdx.x;           // 0..63 (one wave)
  const int rowbase = (b*64 + h*16) * 256;
  const int4* src = (const int4*)(tcode + rowbase);
  #pragma unroll
  for (int i = 0; i < 4; i++) sT4[t + 64*i] = src[t + 64*i];

  int l = c*CHUNK + t;
  int r = (b*LL + l)*HH + h;
  int   xcv = xcode[r];
  float xsv = xss[r];
  __syncthreads();

  int z = carryZ[blk];
  int aReg = 0, zReg = 0;
  for (int k = 0; k < CHUNK; k++){
    int xck = __shfl(xcv, k, 64);
    int a = xck*256 + z;
    z = sT[a];
    if (t == k){ aReg = a; zReg = z; }
  }

  float p = andf(tabs[rowbase + aReg], xsv);
  #pragma unroll
  for (int off = 1; off < 64; off <<= 1){
    float o = __shfl_up(p, off, 64);
    if (t >= off) p = andf(o, p);
  }
  zOut[blk*CHUNK + t] = (uint8_t)zReg;
  P[blk*CHUNK + t] = p;
  if (t == 63) T[blk] = p;
}

// ===== Phase C2: redundant score-carry + coalesced emit =====
__global__ __launch_bounds__(256) void k_C2(const uint8_t* zOut, const float* P,
                                            const float* T, const float* s0s,
                                            float* out){
  int blk = blockIdx.x;          // b*64 + c
  int c = blk & 63;
  int b = blk >> 6;
  __shared__ float carryL[4];
  int t = threadIdx.x;
  int w = t >> 6, lane = t & 63;

  float val = (lane < c) ? T[(b*4 + w)*64 + lane] : AND_IDENT;
  #pragma unroll
  for (int off = 1; off < 64; off <<= 1){
    float o = __shfl_xor(val, off, 64);
    val = andf(val, o);
  }
  float carry = andf(val, s0s[b*4 + w]);
  if (lane == 0) carryL[w] = carry;
  __syncthreads();

  int k = t >> 2, h = t & 3;
  int cblk = (b*4 + h)*64 + c;
  int z = zOut[cblk*CHUNK + k];
  float sc = andf(carryL[h], P[cblk*CHUNK + k]);

  size_t base = (size_t)blk*2048 + (size_t)t*8;
  float4 b0, b1;
  b0.x = (float)((z >> 7) & 1); b0.y = (float)((z >> 6) & 1);
  b0.z = (float)((z >> 5) & 1); b0.w = (float)((z >> 4) & 1);
  b1.x = (float)((z >> 3) & 1); b1.y = (float)((z >> 2) & 1);
  b1.z = (float)((z >> 1) & 1); b1.w = (float)( z       & 1);
  float4 s4; s4.x = sc; s4.y = sc; s4.z = sc; s4.w = sc;
  *(float4*)(out + base)     = b0;
  *(float4*)(out + base + 4) = b1;
  *(float4*)(out + 1048576 + base)     = s4;
  *(float4*)(out + 1048576 + base + 4) = s4;
}

extern "C" void kernel_launch(void* const* d_in, const int* in_sizes, int n_in,
                              void* d_out, int out_size, void* d_ws, size_t ws_size,
                              hipStream_t stream) {
  const void*  x      = d_in[0];
  const float* xs     = (const float*)d_in[1];
  const float* fk     = (const float*)d_in[2];
  const float* fv     = (const float*)d_in[3];
  const float* table  = (const float*)d_in[4];
  const float* s0w    = (const float*)d_in[5];
  float* out          = (float*)d_out;

  uint8_t* ws = (uint8_t*)d_ws;
  uint8_t* xcode_ = ws;                              // 131072 B
  uint8_t* tcode_ = ws + 131072;                     // 131072 B
  uint8_t* F_     = ws + 262144;                     // 524288 B
  float*   xss_   = (float*)(ws + 786432);           // 524288 B
  float*   tabs_  = (float*)(ws + 1310720);          // 524288 B
  uint8_t* zOut_  = ws + 1835008;                    // 131072 B
  float*   P_     = (float*)(ws + 1966080);          // 524288 B
  float*   T_     = (float*)(ws + 2490368);          // 8192 B
  int*     carryZ_= (int*)  (ws + 2498560);          // 8192 B
  int*     s0code_= (int*)  (ws + 2506752);          // 128 B
  float*   s0s_   = (float*)(ws + 2506880);          // 128 B
  int*     flag_  = (int*)  (ws + 2507008);          // 4 B (pad to 2507264)
  float*   sigT_  = (float*)(ws + 2507264);          // 524288 B
  float*   sigFK_ = (float*)(ws + 3031552);          // 65280 B
  float*   sigFV_ = (float*)(ws + 3096832);          // 16384 B
  uint32_t* keys_ = (uint32_t*)(ws + 3113216);       // 256 B

  k_pre  <<<592, 256, 0, stream>>>((const uint32_t*)x, flag_, s0w, s0code_, s0s_,
                                   fk, fv, table, sigT_, sigFK_, sigFV_, keys_);
  k_ffn  <<<NROW/256, 256, 0, stream>>>(x, xs, sigFK_, fv, sigFV_, keys_, xcode_, xss_, flag_);
  k_table<<<131072/256, 256, 0, stream>>>(table, sigT_, tcode_, tabs_);
  k_A    <<<32*NCHUNK, 256, 0, stream>>>(tcode_, xcode_, F_);
  k_B    <<<32, 256, 0, stream>>>(F_, s0code_, carryZ_);
  k_C1   <<<32*NCHUNK, 64, 0, stream>>>(tcode_, tabs_, xcode_, xss_, carryZ_, zOut_, P_, T_);
  k_C2   <<<BB*NCHUNK, 256, 0, stream>>>(zOut_, P_, T_, s0s_, out);
}

// Round 5
// 168.855 us; speedup vs baseline: 1.5060x; 1.5060x over previous
//
#include <hip/hip_runtime.h>
#include <hip/hip_bf16.h>
#include <stdint.h>
#include <math.h>

// ===== Problem constants =====
#define BB 8
#define LL 4096
#define HH 4
#define DD 8      // IN_DIM
#define VV 4      // FFN_V
#define DEPTH 8   // FFN_DEPTH
#define NBIT 8
#define NROW 131072   // B*L*H
#define CHUNK 64
#define NCHUNK 64     // L / CHUNK

__device__ __forceinline__ uint32_t rotl32(uint32_t v, int r){ return (v<<r)|(v>>(32-r)); }

__device__ __forceinline__ void tf2x32(uint32_t k0, uint32_t k1, uint32_t x0, uint32_t x1,
                                       uint32_t& o0, uint32_t& o1){
  uint32_t ks2 = k0 ^ k1 ^ 0x1BD11BDAu;
  x0 += k0; x1 += k1;
  x0+=x1; x1=rotl32(x1,13); x1^=x0;
  x0+=x1; x1=rotl32(x1,15); x1^=x0;
  x0+=x1; x1=rotl32(x1,26); x1^=x0;
  x0+=x1; x1=rotl32(x1, 6); x1^=x0;
  x0+=k1; x1+=ks2+1u;
  x0+=x1; x1=rotl32(x1,17); x1^=x0;
  x0+=x1; x1=rotl32(x1,29); x1^=x0;
  x0+=x1; x1=rotl32(x1,16); x1^=x0;
  x0+=x1; x1=rotl32(x1,24); x1^=x0;
  x0+=ks2; x1+=k0+2u;
  x0+=x1; x1=rotl32(x1,13); x1^=x0;
  x0+=x1; x1=rotl32(x1,15); x1^=x0;
  x0+=x1; x1=rotl32(x1,26); x1^=x0;
  x0+=x1; x1=rotl32(x1, 6); x1^=x0;
  x0+=k0; x1+=k1+3u;
  x0+=x1; x1=rotl32(x1,17); x1^=x0;
  x0+=x1; x1=rotl32(x1,29); x1^=x0;
  x0+=x1; x1=rotl32(x1,16); x1^=x0;
  x0+=x1; x1=rotl32(x1,24); x1^=x0;
  x0+=k1; x1+=ks2+4u;
  x0+=x1; x1=rotl32(x1,13); x1^=x0;
  x0+=x1; x1=rotl32(x1,15); x1^=x0;
  x0+=x1; x1=rotl32(x1,26); x1^=x0;
  x0+=x1; x1=rotl32(x1, 6); x1^=x0;
  x0+=ks2; x1+=k0+5u;
  o0 = x0; o1 = x1;
}

struct K2 { uint32_t a, b; };
__device__ __forceinline__ K2 kfold(K2 k, uint32_t d){
  K2 r; tf2x32(k.a, k.b, 0u, d, r.a, r.b); return r;
}

// partitionable threefry (jax >= 0.4.36 default): bits = o0 ^ o1 of tf(key, [0, p])
__device__ __forceinline__ uint32_t rbits(K2 k, uint32_t p){
  uint32_t o0, o1; tf2x32(k.a, k.b, 0u, p, o0, o1); return o0 ^ o1;
}

__device__ __forceinline__ float bits2u(uint32_t b){
  return __uint_as_float((b >> 9) | 0x3f800000u) - 1.0f;
}

// ===== Bit-exact XLA-CPU style math (Cephes/Eigen structure, strict f32, no FMA) =====
__device__ __forceinline__ float xla_expf(float x){
  #pragma clang fp contract(off)
  const float exp_hi = 88.3762626647950f;
  const float exp_lo = -88.3762626647949f;
  const float log2e  = 1.44269504088896341f;
  const float c1 = 0.693359375f;
  const float c2 = -2.12194440e-4f;
  float xc = fmaxf(fminf(x, exp_hi), exp_lo);
  float fx = floorf(xc * log2e + 0.5f);
  float tmp = fx * c1;
  float z1  = fx * c2;
  float r = xc - tmp;
  r = r - z1;
  float z = r * r;
  float y = 1.9875691500E-4f;
  y = y * r + 1.3981999507E-3f;
  y = y * r + 8.3334519073E-3f;
  y = y * r + 4.1665795894E-2f;
  y = y * r + 1.6666665459E-1f;
  y = y * r + 5.0000001201E-1f;
  y = y * z + r;
  y = y + 1.0f;
  int emm0 = (int)fx + 127;
  float scale = __int_as_float(emm0 << 23);
  return fmaxf(y * scale, x);
}

__device__ __forceinline__ float xla_logf(float a){
  #pragma clang fp contract(off)
  float x = fmaxf(a, __uint_as_float(0x00800000u));
  uint32_t bits = __float_as_uint(x);
  int em = (int)(bits >> 23) - 126;
  x = __uint_as_float((bits & 0x007fffffu) | 0x3f000000u);
  float e = (float)em;
  bool mlt = x < 0.707106781186547524f;
  float tmp1 = mlt ? x : 0.0f;
  float xm = x - 1.0f;
  e = e - (mlt ? 1.0f : 0.0f);
  xm = xm + tmp1;
  float z = xm * xm;
  float y = 7.0376836292E-2f;
  y = y * xm + (-1.1514610310E-1f);
  y = y * xm + 1.1676998740E-1f;
  y = y * xm + (-1.2420140846E-1f);
  y = y * xm + 1.4249322787E-1f;
  y = y * xm + (-1.6668057665E-1f);
  y = y * xm + 2.0000714765E-1f;
  y = y * xm + (-2.4999993993E-1f);
  y = y * xm + 3.3333331174E-1f;
  y = y * xm;
  y = y * z;
  y = e * (-2.12194440e-4f) + y;
  y = y - 0.5f * z;
  float res = xm + y;
  res = e * 0.693359375f + res;
  return res;
}

__device__ __forceinline__ float xla_log1pf(float x){
  #pragma clang fp contract(off)
  if (fabsf(x) < 1e-4f){
    return ((-0.5f * x) + 1.0f) * x;
  }
  return xla_logf(1.0f + x);
}

__device__ __forceinline__ float xla_logaddexp(float a, float b){
  #pragma clang fp contract(off)
  float m = fmaxf(a, b);
  float d = a - b;
  return m + xla_log1pf(xla_expf(-fabsf(d)));
}

template<int NV>
__device__ __forceinline__ float neg_lse_neg(const float* v){
  #pragma clang fp contract(off)
  float m = -v[0];
  #pragma unroll
  for (int i = 1; i < NV; i++) m = fmaxf(m, -v[i]);
  float s = 0.f;
  #pragma unroll
  for (int i = 0; i < NV; i++) s = s + xla_expf((-v[i]) - m);
  return -(xla_logf(s) + m);
}

// sigmoid exactly as XLA LogisticExpander: 1/(1+exp(-w))
__device__ __forceinline__ float xla_sigmoid(float w){
  #pragma clang fp contract(off)
  float e = xla_expf(-w);
  return 1.0f / (1.0f + e);
}

// fast soft-AND for analog-only paths: -logaddexp(-a,-b). andf(x, 1e30f)==x.
__device__ __forceinline__ float andf(float a, float b){
  float na = -a, nb = -b;
  float m = fmaxf(na, nb);
  float d = fabsf(na - nb);
  return -(m + log1pf(expf(-d)));
}
#define AND_IDENT 1e30f

// ===== k_pre (82 blocks): sigFK/sigFV tables + flag + s0 + uniform threefry keys =====
__global__ __launch_bounds__(256) void k_pre(const uint32_t* xw, int* flag,
                      const float* s0w, int* s0code, float* s0s,
                      const float* fk, const float* fv,
                      float* sigFK, float* sigFV, uint32_t* keys){
  int i = blockIdx.x * 256 + threadIdx.x;
  if (i < 16320) sigFK[i] = xla_sigmoid(fk[i]);
  else if (i < 16320 + 4096) sigFV[i - 16320] = xla_sigmoid(fv[i - 16320]);

  if (blockIdx.x == 0){
    __shared__ int any;
    int t = threadIdx.x;
    if (t == 0) any = 0;
    __syncthreads();
    int bad = 0;
    for (int k = t; k < 1024; k += 256){
      uint32_t w = xw[k];
      if (w != 0u && w != 1u && w != 0x3F800000u) bad = 1;
    }
    if (bad) atomicOr(&any, 1);
    __syncthreads();
    if (t == 0) *flag = any;   // 1 -> u8 layout, 0 -> 4-byte layout

    if (t < 32){
      int b = t >> 2, h = t & 3;
      K2 root{0u, 42u};
      K2 sk = kfold(root, 3u);
      float v[NBIT];
      uint32_t code = 0;
      #pragma unroll
      for (int j = 0; j < NBIT; j++){
        float w = s0w[h*NBIT + j];
        uint32_t p = (uint32_t)((b*4 + h)*NBIT + j);
        float u = bits2u(rbits(sk, p));
        bool bit = u < xla_sigmoid(w);
        code |= (bit ? 1u : 0u) << (NBIT - 1 - j);
        v[j] = bit ? w : -w;
      }
      s0code[t] = (int)code;
      s0s[t]    = neg_lse_neg<NBIT>(v);
    }
    if (t == 0){
      K2 root{0u, 42u};
      K2 rngT = kfold(root, 1u);
      for (int d = 0; d < DEPTH; d++){
        K2 kd = kfold(rngT, (uint32_t)d);
        keys[2*d] = kd.a; keys[2*d+1] = kd.b;
        K2 lk = kfold(rngT, 100u + (uint32_t)d);
        keys[16+2*d] = lk.a; keys[16+2*d+1] = lk.b;
      }
      K2 vk = kfold(rngT, 999u);
      keys[32] = vk.a; keys[33] = vk.b;
      K2 tk = kfold(root, 2u);
      keys[34] = tk.a; keys[35] = tk.b;
    }
  }
}

// ===== k_main (1024 blocks): blk<512 -> tree-FFN rows; blk>=512 -> table rows =====
__global__ __launch_bounds__(256, 2) void k_main(const void* xraw, const float* xs,
                                             const float* sigFK,
                                             const float* fv, const float* sigFV,
                                             const float* table,
                                             const uint32_t* keys, const int* flag,
                                             uint8_t* xcode, float* xss,
                                             uint8_t* tcode, float* tabs){
  int blk = blockIdx.x;
  int t = threadIdx.x;

  if (blk >= 512){
    // ---- table path (round-3-verified bit-exact) ----
    int idx = (blk - 512) * 256 + t;
    int rem = idx & 16383;
    K2 tk{keys[34], keys[35]};
    float4 w0 = *(const float4*)(table + (size_t)rem*NBIT);
    float4 w1 = *(const float4*)(table + (size_t)rem*NBIT + 4);
    float w[NBIT] = {w0.x,w0.y,w0.z,w0.w,w1.x,w1.y,w1.z,w1.w};
    float v[NBIT];
    uint32_t code = 0;
    #pragma unroll
    for (int j = 0; j < NBIT; j++){
      float u = bits2u(rbits(tk, (uint32_t)idx * 8u + (uint32_t)j));
      bool bit = u < xla_sigmoid(w[j]);
      code |= (bit ? 1u : 0u) << (NBIT - 1 - j);
      v[j] = bit ? w[j] : -w[j];
    }
    tcode[idx] = (uint8_t)code;
    tabs[idx]  = neg_lse_neg<NBIT>(v);
    return;
  }

  // ---- FFN path ----
  int r = blk * 256 + t;
  int n = r >> 2;
  int h = r & 3;
  bool u8mode = (*flag != 0);
  const uint8_t* x8   = (const uint8_t*)xraw;
  const uint32_t* x32 = (const uint32_t*)xraw;

  // L[sel][j], sel = (b2<<1)|b1 — identical op sequence to reference per (d,j)
  float L0[DD], L1[DD], L2[DD], L3[DD];
  #pragma unroll
  for (int j = 0; j < DD; j++){
    bool qb = u8mode ? (x8[n*DD + j] != 0) : (x32[n*DD + j] != 0u);
    float v = xs[n*DD + j];
    float q = qb ? v : -v;
    float A0 = -xla_logaddexp(-0.0f, q);
    float A1 = -xla_logaddexp(-1.0f, q);
    float B0 = -xla_logaddexp(-0.0f, -q);
    float B1 = -xla_logaddexp(-1.0f, -q);
    L0[j] = xla_logaddexp(A0, B0);
    L1[j] = xla_logaddexp(A1, B0);
    L2[j] = xla_logaddexp(A0, B1);
    L3[j] = xla_logaddexp(A1, B1);
  }

  const float* hb = sigFK + (size_t)h * 255 * 16;
  // preload root node sigmoids (node 0)
  float cur[16];
  #pragma unroll
  for (int q4 = 0; q4 < 4; q4++)
    *(float4*)(cur + 4*q4) = *(const float4*)(hb + 4*q4);

  uint32_t ix = 0;
  float support = 0.f;

  for (int d = 0; d < 7; d++){
    // speculative prefetch of both children (level d+1) — overlaps this depth's compute
    float cl[16], cr[16];
    {
      const float* cb = hb + (size_t)((2 << d) - 1 + 2*(int)ix) * 16;
      #pragma unroll
      for (int q4 = 0; q4 < 4; q4++){
        *(float4*)(cl + 4*q4) = *(const float4*)(cb + 4*q4);
        *(float4*)(cr + 4*q4) = *(const float4*)(cb + 16 + 4*q4);
      }
    }
    K2 kd{keys[2*d], keys[2*d+1]};
    float lor[DD];
    #pragma unroll
    for (int j = 0; j < DD; j++){
      uint32_t p1 = (uint32_t)r * 16u + 2u*(uint32_t)j;
      float u1 = bits2u(rbits(kd, p1));
      float u2 = bits2u(rbits(kd, p1 + 1u));
      bool b1 = u1 < cur[2*j];
      bool b2 = u2 < cur[2*j + 1];
      float t01 = b1 ? L1[j] : L0[j];
      float t23 = b1 ? L3[j] : L2[j];
      lor[j] = b2 ? t23 : t01;
    }
    float lor_s = neg_lse_neg<DD>(lor);
    K2 lk{keys[16+2*d], keys[16+2*d+1]};
    float ul = bits2u(rbits(lk, (uint32_t)r));
    bool lb = ul < xla_sigmoid(lor_s);
    float ls = lb ? lor_s : -lor_s;
    ix = 2u*ix + (lb ? 1u : 0u);
    support = (d == 0) ? ls : -xla_logaddexp(-support, -ls);
    #pragma unroll
    for (int q = 0; q < 16; q++) cur[q] = lb ? cr[q] : cl[q];
  }

  // depth 7 (peeled): prefetch both leaf value rows (8 contiguous floats each)
  float fvv[8], sfv[8];
  {
    const float* fb = fv    + (size_t)(h*256 + 2*(int)ix) * VV;
    const float* sb = sigFV + (size_t)(h*256 + 2*(int)ix) * VV;
    *(float4*)(fvv)     = *(const float4*)(fb);
    *(float4*)(fvv + 4) = *(const float4*)(fb + 4);
    *(float4*)(sfv)     = *(const float4*)(sb);
    *(float4*)(sfv + 4) = *(const float4*)(sb + 4);
  }
  {
    const int d = 7;
    K2 kd{keys[2*d], keys[2*d+1]};
    float lor[DD];
    #pragma unroll
    for (int j = 0; j < DD; j++){
      uint32_t p1 = (uint32_t)r * 16u + 2u*(uint32_t)j;
      float u1 = bits2u(rbits(kd, p1));
      float u2 = bits2u(rbits(kd, p1 + 1u));
      bool b1 = u1 < cur[2*j];
      bool b2 = u2 < cur[2*j + 1];
      float t01 = b1 ? L1[j] : L0[j];
      float t23 = b1 ? L3[j] : L2[j];
      lor[j] = b2 ? t23 : t01;
    }
    float lor_s = neg_lse_neg<DD>(lor);
    K2 lk{keys[16+2*d], keys[16+2*d+1]};
    float ul = bits2u(rbits(lk, (uint32_t)r));
    bool lb = ul < xla_sigmoid(lor_s);
    float ls = lb ? lor_s : -lor_s;
    support = -xla_logaddexp(-support, -ls);
    #pragma unroll
    for (int c = 0; c < VV; c++){
      fvv[c] = lb ? fvv[4+c] : fvv[c];
      sfv[c] = lb ? sfv[4+c] : sfv[c];
    }
  }

  K2 vk{keys[32], keys[33]};
  float vs[VV];
  uint32_t code = 0;
  #pragma unroll
  for (int c = 0; c < VV; c++){
    float u = bits2u(rbits(vk, (uint32_t)r*4u + (uint32_t)c));
    bool b = u < sfv[c];
    code |= (b ? 1u : 0u) << (VV - 1 - c);
    float sv = b ? fvv[c] : -fvv[c];
    vs[c] = -xla_logaddexp(-sv, -support);
  }
  xcode[r] = (uint8_t)code;
  xss[r]   = neg_lse_neg<VV>(vs);
}

// ===== Phase A: per-chunk all-state map F (states only) =====
__global__ __launch_bounds__(256) void k_A(const uint8_t* tcode, const uint8_t* xcode,
                                           uint8_t* F){
  int blk = blockIdx.x;          // (b*4+h)*64 + c
  int c  = blk & 63;
  int bh = blk >> 6;
  int b = bh >> 2, h = bh & 3;
  __shared__ int4 sT4[256];
  __shared__ uint8_t sXC[CHUNK];
  uint8_t* sT = (uint8_t*)sT4;
  int t = threadIdx.x;
  const int rowbase = (b*64 + h*16) * 256;
  sT4[t] = ((const int4*)(tcode + rowbase))[t];
  if (t < CHUNK){
    int l = c*CHUNK + t;
    sXC[t] = xcode[(b*LL + l)*HH + h];
  }
  __syncthreads();
  int cur = t;
  #pragma unroll 8
  for (int k = 0; k < CHUNK; k++){
    cur = sT[(int)sXC[k]*256 + cur];
  }
  F[(size_t)blk*256 + t] = (uint8_t)cur;
}

// ===== Phase C1 (with fused carry chase): replay chunk + score scan =====
__global__ __launch_bounds__(64) void k_C1(const uint8_t* tcode, const float* tabs,
                                           const uint8_t* xcode, const float* xss,
                                           const uint8_t* F, const int* s0code,
                                           uint8_t* zOut, float* P, float* T){
  int blk = blockIdx.x;          // (b*4+h)*64 + c
  int c  = blk & 63;
  int bh = blk >> 6;
  int b = bh >> 2, h = bh & 3;
  __shared__ int4 sT4[256];
  uint8_t* sT = (uint8_t*)sT4;
  int t = threadIdx.x;           // 0..63 (one wave)
  const int rowbase = (b*64 + h*16) * 256;
  const int4* src = (const int4*)(tcode + rowbase);
  #pragma unroll
  for (int i = 0; i < 4; i++) sT4[t + 64*i] = src[t + 64*i];

  int l = c*CHUNK + t;
  int r = (b*LL + l)*HH + h;
  int   xcv = xcode[r];
  float xsv = xss[r];

  // redundant carry chase through per-chunk maps (broadcast L2 loads)
  int z = s0code[bh];
  const uint8_t* Fb = F + (size_t)bh * 16384;
  for (int k = 0; k < c; k++) z = Fb[k*256 + z];
  __syncthreads();

  // redundant all-lane chase within this chunk
  int aReg = 0, zReg = 0;
  for (int k = 0; k < CHUNK; k++){
    int xck = __shfl(xcv, k, 64);
    int a = xck*256 + z;
    z = sT[a];
    if (t == k){ aReg = a; zReg = z; }
  }

  float p = andf(tabs[rowbase + aReg], xsv);
  #pragma unroll
  for (int off = 1; off < 64; off <<= 1){
    float o = __shfl_up(p, off, 64);
    if (t >= off) p = andf(o, p);
  }
  zOut[blk*CHUNK + t] = (uint8_t)zReg;
  P[blk*CHUNK + t] = p;
  if (t == 63) T[blk] = p;
}

// ===== Phase C2: redundant score-carry + coalesced emit =====
__global__ __launch_bounds__(256) void k_C2(const uint8_t* zOut, const float* P,
                                            const float* T, const float* s0s,
                                            float* out){
  int blk = blockIdx.x;          // b*64 + c
  int c = blk & 63;
  int b = blk >> 6;
  __shared__ float carryL[4];
  int t = threadIdx.x;
  int w = t >> 6, lane = t & 63;

  float val = (lane < c) ? T[(b*4 + w)*64 + lane] : AND_IDENT;
  #pragma unroll
  for (int off = 1; off < 64; off <<= 1){
    float o = __shfl_xor(val, off, 64);
    val = andf(val, o);
  }
  float carry = andf(val, s0s[b*4 + w]);
  if (lane == 0) carryL[w] = carry;
  __syncthreads();

  int k = t >> 2, h = t & 3;
  int cblk = (b*4 + h)*64 + c;
  int z = zOut[cblk*CHUNK + k];
  float sc = andf(carryL[h], P[cblk*CHUNK + k]);

  size_t base = (size_t)blk*2048 + (size_t)t*8;
  float4 b0, b1;
  b0.x = (float)((z >> 7) & 1); b0.y = (float)((z >> 6) & 1);
  b0.z = (float)((z >> 5) & 1); b0.w = (float)((z >> 4) & 1);
  b1.x = (float)((z >> 3) & 1); b1.y = (float)((z >> 2) & 1);
  b1.z = (float)((z >> 1) & 1); b1.w = (float)( z       & 1);
  float4 s4; s4.x = sc; s4.y = sc; s4.z = sc; s4.w = sc;
  *(float4*)(out + base)     = b0;
  *(float4*)(out + base + 4) = b1;
  *(float4*)(out + 1048576 + base)     = s4;
  *(float4*)(out + 1048576 + base + 4) = s4;
}

extern "C" void kernel_launch(void* const* d_in, const int* in_sizes, int n_in,
                              void* d_out, int out_size, void* d_ws, size_t ws_size,
                              hipStream_t stream) {
  const void*  x      = d_in[0];
  const float* xs     = (const float*)d_in[1];
  const float* fk     = (const float*)d_in[2];
  const float* fv     = (const float*)d_in[3];
  const float* table  = (const float*)d_in[4];
  const float* s0w    = (const float*)d_in[5];
  float* out          = (float*)d_out;

  uint8_t* ws = (uint8_t*)d_ws;
  uint8_t* xcode_ = ws;                              // 131072 B
  uint8_t* tcode_ = ws + 131072;                     // 131072 B
  uint8_t* F_     = ws + 262144;                     // 524288 B
  float*   xss_   = (float*)(ws + 786432);           // 524288 B
  float*   tabs_  = (float*)(ws + 1310720);          // 524288 B
  uint8_t* zOut_  = ws + 1835008;                    // 131072 B
  float*   P_     = (float*)(ws + 1966080);          // 524288 B
  float*   T_     = (float*)(ws + 2490368);          // 8192 B
  int*     s0code_= (int*)  (ws + 2498560);          // 128 B
  float*   s0s_   = (float*)(ws + 2498688);          // 128 B
  int*     flag_  = (int*)  (ws + 2498816);          // 4 B (pad to 2499072)
  float*   sigFK_ = (float*)(ws + 2499072);          // 65280 B
  float*   sigFV_ = (float*)(ws + 2564352);          // 16384 B
  uint32_t* keys_ = (uint32_t*)(ws + 2580736);       // 144 B

  k_pre <<<82, 256, 0, stream>>>((const uint32_t*)x, flag_, s0w, s0code_, s0s_,
                                 fk, fv, sigFK_, sigFV_, keys_);
  k_main<<<1024, 256, 0, stream>>>(x, xs, sigFK_, fv, sigFV_, table, keys_, flag_,
                                   xcode_, xss_, tcode_, tabs_);
  k_A   <<<32*NCHUNK, 256, 0, stream>>>(tcode_, xcode_, F_);
  k_C1  <<<32*NCHUNK, 64, 0, stream>>>(tcode_, tabs_, xcode_, xss_, F_, s0code_,
                                       zOut_, P_, T_);
  k_C2  <<<BB*NCHUNK, 256, 0, stream>>>(zOut_, P_, T_, s0s_, out);
}